// Round 2
// baseline (72.835 us; speedup 1.0000x reference)
//
#include <hip/hip_runtime.h>

#define N_NODES 2048
#define WORDS   64          // N_NODES / 32
#define E_MAX_OUT 1048576
#define FDIM    8

// ws layout: a_bits | c_bits | row_cnt | row_off | ctr
// ---------------- init: fill d_out pattern + zero a_bits + ctr ----------------
__global__ void k_init(float* __restrict__ out, unsigned* __restrict__ a_bits,
                       unsigned* __restrict__ ctr) {
    int tid = blockIdx.x * blockDim.x + threadIdx.x;
    int nthreads = gridDim.x * blockDim.x;
    const int TOTAL4 = (2 * E_MAX_OUT + FDIM * E_MAX_OUT) / 4;  // 2,621,440 float4
    const int NEG4   = (2 * E_MAX_OUT) / 4;                     // rows|cols = -1
    float4* o4 = (float4*)out;
    for (int p = tid; p < TOTAL4; p += nthreads) {
        float v = (p < NEG4) ? -1.0f : 0.0f;
        o4[p] = make_float4(v, v, v, v);
    }
    for (int p = tid; p < N_NODES * WORDS; p += nthreads) a_bits[p] = 0u;
    if (tid == 0) *ctr = 0u;
}

// ---------------- build adjacency bitset ----------------
__global__ void k_build(const int* __restrict__ ei, int E, unsigned* __restrict__ a_bits) {
    int e = blockIdx.x * blockDim.x + threadIdx.x;
    if (e >= E) return;
    int s = ei[e];
    int d = ei[E + e];
    atomicOr(&a_bits[s * WORDS + (d >> 5)], 1u << (d & 31));
}

// ---------------- two-hop + fused last-block prefix scan ----------------
// 256 threads = 4 waves per row. Neighbor list compacted to LDS, then split
// across waves with unrolled independent loads (pipelined L2 hits).
__global__ void __launch_bounds__(256) k_twohop(const unsigned* __restrict__ a_bits,
                                                unsigned* __restrict__ c_bits,
                                                int* __restrict__ row_cnt,
                                                int* __restrict__ row_off,
                                                unsigned* __restrict__ ctr) {
    int i    = blockIdx.x;
    int tid  = threadIdx.x;
    int lane = tid & 63;
    int wave = tid >> 6;
    __shared__ unsigned rowi[WORDS];
    __shared__ int      nbr[N_NODES];     // worst case one full row
    __shared__ int      ncnt_sh;
    __shared__ unsigned partial[4][WORDS];

    if (wave == 0) {
        unsigned r = a_bits[i * WORDS + lane];
        rowi[lane] = r;
        int pc = __popc(r);
        int incl = pc;
        for (int off = 1; off < 64; off <<= 1) {
            int v = __shfl_up(incl, off, 64);
            if (lane >= off) incl += v;
        }
        int base = incl - pc;
        unsigned bits = r;
        int wb = lane << 5;
        while (bits) {
            int b = __ffs(bits) - 1;
            bits &= bits - 1;
            nbr[base++] = wb + b;
        }
        if (lane == 63) ncnt_sh = incl;
    }
    __syncthreads();
    int ncnt = ncnt_sh;

    unsigned acc = 0u;
    int j = wave;
    for (; j + 4 < ncnt; j += 8) {                 // 2 independent loads/iter
        unsigned x0 = a_bits[nbr[j]     * WORDS + lane];
        unsigned x1 = a_bits[nbr[j + 4] * WORDS + lane];
        acc |= x0 | x1;
    }
    if (j < ncnt) acc |= a_bits[nbr[j] * WORDS + lane];
    partial[wave][lane] = acc;
    __syncthreads();

    if (wave == 0) {
        acc = partial[0][lane] | partial[1][lane] | partial[2][lane] | partial[3][lane];
        if (lane == (i >> 5)) acc &= ~(1u << (i & 31));  // remove self-loop
        acc |= rowi[lane];                                // union original
        c_bits[i * WORDS + lane] = acc;
        int cnt = __popc(acc);
        for (int off = 32; off; off >>= 1) cnt += __shfl_down(cnt, off, 64);
        if (lane == 0) row_cnt[i] = cnt;
    }
    __syncthreads();

    // last finishing block performs the 2048-entry exclusive scan
    if (tid == 0) {
        __threadfence();
        unsigned done = atomicAdd(ctr, 1u);
        ncnt_sh = (done == N_NODES - 1) ? 1 : 0;   // reuse LDS slot as flag
    }
    __syncthreads();
    if (ncnt_sh != 0 && wave == 0) {
        __threadfence();
        int base = lane * 32;
        int c[32];
        int s = 0;
        #pragma unroll
        for (int q = 0; q < 32; ++q) { c[q] = row_cnt[base + q]; s += c[q]; }
        int incl = s;
        for (int off = 1; off < 64; off <<= 1) {
            int v = __shfl_up(incl, off, 64);
            if (lane >= off) incl += v;
        }
        int run = incl - s;
        #pragma unroll
        for (int q = 0; q < 32; ++q) { row_off[base + q] = run; run += c[q]; }
        if (lane == 63) row_off[N_NODES] = incl;
    }
}

// ---------------- fused emit + attr ----------------
// 2048 blocks x 128 threads: wave 0 emits row i, wave 1 scatters attrs for
// edges [i*16, i*16+16) with 4 lanes per edge (parallel popcount rank).
__global__ void __launch_bounds__(128) k_emit_attr(const unsigned* __restrict__ c_bits,
                                                   const int* __restrict__ row_off,
                                                   const int* __restrict__ ei,
                                                   const float* __restrict__ attr, int E,
                                                   float* __restrict__ out) {
    int i    = blockIdx.x;
    int lane = threadIdx.x & 63;
    int wave = threadIdx.x >> 6;

    if (wave == 0) {
        unsigned c = c_bits[i * WORDS + lane];
        int pc = __popc(c);
        int incl = pc;
        for (int off = 1; off < 64; off <<= 1) {
            int v = __shfl_up(incl, off, 64);
            if (lane >= off) incl += v;
        }
        int p = row_off[i] + incl - pc;
        float fi = (float)i;
        int wb = lane << 5;
        unsigned bits = c;
        while (bits) {
            int b = __ffs(bits) - 1;
            bits &= bits - 1;
            if (p < E_MAX_OUT) {
                out[p]             = fi;
                out[E_MAX_OUT + p] = (float)(wb + b);
            }
            ++p;
        }
    } else {
        int le = lane >> 2;          // edge slot 0..15
        int q  = lane & 3;           // quarter
        for (int e = i * 16 + le; e < E; e += N_NODES * 16) {
            int s = ei[e];
            int d = ei[E + e];
            const unsigned* row = c_bits + s * WORDS;
            int dw = d >> 5;
            int r = 0;
            int w0 = q * 16;
            int w1 = (dw < w0 + 16) ? dw : (w0 + 16);
            for (int w = w0; w < w1; ++w) r += __popc(row[w]);
            if (q == 0) r += __popc(row[dw] & ((1u << (d & 31)) - 1u));
            r += __shfl_xor(r, 1, 4);
            r += __shfl_xor(r, 2, 4);
            int p = row_off[s] + r;
            if (p < E_MAX_OUT) {
                float* dst = out + 2 * E_MAX_OUT + p * FDIM;
                atomicAdd(&dst[2 * q],     attr[e * FDIM + 2 * q]);
                atomicAdd(&dst[2 * q + 1], attr[e * FDIM + 2 * q + 1]);
            }
        }
    }
}

extern "C" void kernel_launch(void* const* d_in, const int* in_sizes, int n_in,
                              void* d_out, int out_size, void* d_ws, size_t ws_size,
                              hipStream_t stream) {
    const int*   ei   = (const int*)d_in[1];     // [2, E]
    const float* attr = (const float*)d_in[2];   // [E, 8]
    int E = in_sizes[1] / 2;

    float* out = (float*)d_out;                  // rows | cols | attrs
    unsigned char* ws = (unsigned char*)d_ws;
    unsigned* a_bits  = (unsigned*)(ws);                        // 512 KB
    unsigned* c_bits  = (unsigned*)(ws + 512 * 1024);           // 512 KB
    int*      row_cnt = (int*)(ws + 1024 * 1024);               // 8 KB
    int*      row_off = (int*)(ws + 1024 * 1024 + 16 * 1024);   // 8 KB + 4
    unsigned* ctr     = (unsigned*)(ws + 1024 * 1024 + 32 * 1024);

    k_init     <<<2048, 256, 0, stream>>>(out, a_bits, ctr);
    k_build    <<<(E + 255) / 256, 256, 0, stream>>>(ei, E, a_bits);
    k_twohop   <<<N_NODES, 256, 0, stream>>>(a_bits, c_bits, row_cnt, row_off, ctr);
    k_emit_attr<<<N_NODES, 128, 0, stream>>>(c_bits, row_off, ei, attr, E, out);
}

// Round 3
// 30.009 us; speedup vs baseline: 2.4271x; 2.4271x over previous
//
#include <hip/hip_runtime.h>

#define N_NODES 2048
#define WORDS   64          // N_NODES / 32
#define E_MAX_OUT 1048576
#define FDIM    8

// ws layout: a_bits(512K) | c_bits(512K) | rel_off(512K) | row_cnt(8K) | row_off(8K+4)

// ---------------- init: fill d_out pattern + zero a_bits ----------------
__global__ void k_init(float* __restrict__ out, unsigned* __restrict__ a_bits) {
    int tid = blockIdx.x * blockDim.x + threadIdx.x;
    int nthreads = gridDim.x * blockDim.x;
    const int TOTAL4 = (2 * E_MAX_OUT + FDIM * E_MAX_OUT) / 4;  // 2,621,440 float4
    const int NEG4   = (2 * E_MAX_OUT) / 4;                     // rows|cols = -1
    float4* o4 = (float4*)out;
    for (int p = tid; p < TOTAL4; p += nthreads) {
        float v = (p < NEG4) ? -1.0f : 0.0f;
        o4[p] = make_float4(v, v, v, v);
    }
    for (int p = tid; p < N_NODES * WORDS; p += nthreads) a_bits[p] = 0u;
}

// ---------------- build adjacency bitset ----------------
__global__ void k_build(const int* __restrict__ ei, int E, unsigned* __restrict__ a_bits) {
    int e = blockIdx.x * blockDim.x + threadIdx.x;
    if (e >= E) return;
    int s = ei[e];
    int d = ei[E + e];
    atomicOr(&a_bits[s * WORDS + (d >> 5)], 1u << (d & 31));
}

// ---------------- two-hop: one wave per row, 4 rows per block ----------------
// C[i] = (OR_{k in nbr(i)} A[k]) & ~eye | A[i]; also per-word within-row
// exclusive popcount prefix (rel_off) and per-row count.
__global__ void __launch_bounds__(256) k_twohop(const unsigned* __restrict__ a_bits,
                                                unsigned* __restrict__ c_bits,
                                                int* __restrict__ rel_off,
                                                int* __restrict__ row_cnt) {
    int lane = threadIdx.x & 63;
    int wv   = threadIdx.x >> 6;
    int i    = blockIdx.x * 4 + wv;          // row for this wave
    __shared__ int nbr[4][256];
    __shared__ int ncnt_sh[4];

    // compact neighbor list of row i into LDS (wave-local)
    unsigned r = a_bits[i * WORDS + lane];
    int pc = __popc(r);
    int incl = pc;
    for (int off = 1; off < 64; off <<= 1) {
        int v = __shfl_up(incl, off, 64);
        if (lane >= off) incl += v;
    }
    int base = incl - pc;
    unsigned bits = r;
    int wb = lane << 5;
    while (bits) {
        int b = __ffs(bits) - 1;
        bits &= bits - 1;
        nbr[wv][base++] = wb + b;
    }
    if (lane == 63) ncnt_sh[wv] = incl;
    __syncthreads();

    // counted loop, 4 independent loads in flight
    int nc = ncnt_sh[wv];
    const int* nb = nbr[wv];
    unsigned acc = 0u;
    int j = 0;
    for (; j + 4 <= nc; j += 4) {
        unsigned x0 = a_bits[nb[j]     * WORDS + lane];
        unsigned x1 = a_bits[nb[j + 1] * WORDS + lane];
        unsigned x2 = a_bits[nb[j + 2] * WORDS + lane];
        unsigned x3 = a_bits[nb[j + 3] * WORDS + lane];
        acc |= (x0 | x1) | (x2 | x3);
    }
    for (; j < nc; ++j) acc |= a_bits[nb[j] * WORDS + lane];

    if (lane == (i >> 5)) acc &= ~(1u << (i & 31));  // remove self-loop (two-hop)
    acc |= r;                                         // union original edges
    c_bits[i * WORDS + lane] = acc;

    int cnt = __popc(acc);
    int incl2 = cnt;
    for (int off = 1; off < 64; off <<= 1) {
        int v = __shfl_up(incl2, off, 64);
        if (lane >= off) incl2 += v;
    }
    rel_off[i * WORDS + lane] = incl2 - cnt;   // within-row exclusive word offset
    if (lane == 63) row_cnt[i] = incl2;
}

// ---------------- exclusive prefix over 2048 row counts (1 wave) ----------------
__global__ void __launch_bounds__(64) k_scan(const int* __restrict__ row_cnt,
                                             int* __restrict__ row_off) {
    int t = threadIdx.x;
    int base = t * 32;
    int c[32];
    int s = 0;
    #pragma unroll
    for (int q = 0; q < 32; ++q) { c[q] = row_cnt[base + q]; s += c[q]; }
    int incl = s;
    for (int off = 1; off < 64; off <<= 1) {
        int v = __shfl_up(incl, off, 64);
        if (t >= off) incl += v;
    }
    int run = incl - s;
    #pragma unroll
    for (int q = 0; q < 32; ++q) { row_off[base + q] = run; run += c[q]; }
    if (t == 63) row_off[N_NODES] = incl;
}

// ---------------- fused emit + attr (O(1) edge rank via rel_off) ----------------
__global__ void __launch_bounds__(128) k_emit_attr(const unsigned* __restrict__ c_bits,
                                                   const int* __restrict__ rel_off,
                                                   const int* __restrict__ row_off,
                                                   const int* __restrict__ ei,
                                                   const float* __restrict__ attr, int E,
                                                   float* __restrict__ out) {
    int i    = blockIdx.x;
    int lane = threadIdx.x & 63;
    int wave = threadIdx.x >> 6;

    if (wave == 0) {
        // emit rows/cols for row i
        unsigned c = c_bits[i * WORDS + lane];
        int p = row_off[i] + rel_off[i * WORDS + lane];
        float fi = (float)i;
        int wb = lane << 5;
        unsigned bits = c;
        while (bits) {
            int b = __ffs(bits) - 1;
            bits &= bits - 1;
            if (p < E_MAX_OUT) {
                out[p]             = fi;
                out[E_MAX_OUT + p] = (float)(wb + b);
            }
            ++p;
        }
    } else {
        // scatter attrs: 16 edges per block, 4 lanes per edge (2 floats each)
        float* oattr = out + 2 * E_MAX_OUT;
        for (int e = i * 16 + (lane >> 2); e < E; e += N_NODES * 16) {
            int s = ei[e];
            int d = ei[E + e];
            int dw = d >> 5;
            unsigned cw = c_bits[s * WORDS + dw];
            int p = row_off[s] + rel_off[s * WORDS + dw]
                  + __popc(cw & ((1u << (d & 31)) - 1u));
            if (p < E_MAX_OUT) {
                int q = lane & 3;
                atomicAdd(&oattr[p * FDIM + 2 * q],     attr[e * FDIM + 2 * q]);
                atomicAdd(&oattr[p * FDIM + 2 * q + 1], attr[e * FDIM + 2 * q + 1]);
            }
        }
    }
}

extern "C" void kernel_launch(void* const* d_in, const int* in_sizes, int n_in,
                              void* d_out, int out_size, void* d_ws, size_t ws_size,
                              hipStream_t stream) {
    const int*   ei   = (const int*)d_in[1];     // [2, E]
    const float* attr = (const float*)d_in[2];   // [E, 8]
    int E = in_sizes[1] / 2;

    float* out = (float*)d_out;                  // rows | cols | attrs
    unsigned char* ws = (unsigned char*)d_ws;
    unsigned* a_bits  = (unsigned*)(ws);                         // 512 KB
    unsigned* c_bits  = (unsigned*)(ws + 512 * 1024);            // 512 KB
    int*      rel_off = (int*)(ws + 1024 * 1024);                // 512 KB
    int*      row_cnt = (int*)(ws + 1536 * 1024);                // 8 KB
    int*      row_off = (int*)(ws + 1536 * 1024 + 16 * 1024);    // 8 KB + 4

    k_init     <<<2048, 256, 0, stream>>>(out, a_bits);
    k_build    <<<(E + 255) / 256, 256, 0, stream>>>(ei, E, a_bits);
    k_twohop   <<<N_NODES / 4, 256, 0, stream>>>(a_bits, c_bits, rel_off, row_cnt);
    k_scan     <<<1, 64, 0, stream>>>(row_cnt, row_off);
    k_emit_attr<<<N_NODES, 128, 0, stream>>>(c_bits, rel_off, row_off, ei, attr, E, out);
}